// Round 2
// baseline (412.725 us; speedup 1.0000x reference)
//
#include <hip/hip_runtime.h>
#include <stdint.h>

// Problem constants
#define B_  2
#define T_  2048
#define C_  2048
#define H_  16
#define D_  128
#define BH_ 32        // B*H
#define M_  4096      // B*T

typedef __attribute__((ext_vector_type(8))) __bf16  bf16x8;
typedef __attribute__((ext_vector_type(4))) float   floatx4;
typedef __attribute__((ext_vector_type(4))) ushort  ushortx4;
typedef __attribute__((ext_vector_type(8))) ushort  ushortx8;

__device__ __forceinline__ ushort f2bf(float f) {
    union { float f; uint32_t u; } v; v.f = f;
    return (ushort)((v.u + 0x7fffu + ((v.u >> 16) & 1u)) >> 16);
}

__device__ __forceinline__ float bf2f(ushort u) {
    union { uint32_t u; float f; } v; v.u = ((uint32_t)u) << 16;
    return v.f;
}

__device__ __forceinline__ floatx4 mfma_bf16(bf16x8 a, bf16x8 b, floatx4 c) {
    return __builtin_amdgcn_mfma_f32_16x16x32_bf16(a, b, c, 0, 0, 0);
}

// async global->LDS, 16B per lane; lds dest = wave-uniform base + lane*16
__device__ __forceinline__ void async16(const ushort* g, ushort* l) {
    __builtin_amdgcn_global_load_lds(
        (const __attribute__((address_space(1))) uint32_t*)g,
        (__attribute__((address_space(3))) uint32_t*)l, 16, 0, 0);
}

// ---------------------------------------------------------------------------
// x f32 -> bf16 (vectorized 4-wide)
// ---------------------------------------------------------------------------
__global__ __launch_bounds__(256) void convert_bf16(
    const float* __restrict__ X, ushort* __restrict__ Xb)
{
    const int i = blockIdx.x * 256 + threadIdx.x;
    const float4 v = ((const float4*)X)[i];
    ushortx4 p = { f2bf(v.x), f2bf(v.y), f2bf(v.z), f2bf(v.w) };
    ((ushortx4*)Xb)[i] = p;
}

// ---------------------------------------------------------------------------
// Transpose + convert: W f32 [K][N] -> Wt bf16 [N][K]
// ---------------------------------------------------------------------------
__global__ __launch_bounds__(256) void transpose_w(
    const float* __restrict__ W, ushort* __restrict__ Wt, int Kdim, int Ndim)
{
    __shared__ float tile[32][33];
    const int n0 = blockIdx.x * 32, k0 = blockIdx.y * 32;
    const int tx = threadIdx.x, ty = threadIdx.y;
    #pragma unroll
    for (int j = 0; j < 4; j++)
        tile[ty + j*8][tx] = W[(size_t)(k0 + ty + j*8) * Ndim + n0 + tx];
    __syncthreads();
    #pragma unroll
    for (int j = 0; j < 4; j++)
        Wt[(size_t)(n0 + ty + j*8) * Kdim + k0 + tx] = f2bf(tile[tx][ty + j*8]);
}

// ---------------------------------------------------------------------------
// Shared 8-phase 256x256 K-loop (T1+T2+T3+T4+T5, m201 template shape).
//   512 threads = 8 waves (2M x 4N), per-wave 128x64 output, BK=64, K=2048.
//   LDS: 2 dbuf x (A 32KB + B 32KB) = 128 KiB. XOR-swizzle unit ^= row&7,
//   applied on BOTH sides (pre-swizzled global_load_lds source + swizzled
//   ds_read address) per rule #21; LDS dest stays linear.
//   4 phases per K-tile, quadrant order (m0n0),(m0n1),(m1n0),(m1n1):
//     ph1: read A-m0 + B-n0                      (A blocks {0,2} dead after)
//     ph2: read B-n1; stage A{0,2} of t+2        (B rows all dead after)
//     ph3: read A-m1; stage B{0,1,2} of t+2      (A blocks {1,3} dead after)
//     ph4: stage B{3},A{1,3} of t+2; vmcnt(8)    (tile t+1 resident)
//   vmcnt ledger: 8 loads/tile; steady state 16 outstanding at ph4,
//   vmcnt(8) retires exactly tile t+1. Tail (t>=30) drains vmcnt(0).
//   Every inline-asm waitcnt is followed by sched_barrier(0) (rule #18).
// ---------------------------------------------------------------------------
struct FragA { bf16x8 f[4][2]; };
struct FragB { bf16x8 f[2][2]; };

__device__ __forceinline__ void load_a(FragA& fa, const ushort* Ab, int base,
                                       int lr, int quad)
{
    #pragma unroll
    for (int mi2 = 0; mi2 < 4; mi2++)
        #pragma unroll
        for (int kk = 0; kk < 2; kk++) {
            const int row = base + mi2 * 16 + lr;
            fa.f[mi2][kk] = *(const bf16x8*)(
                Ab + row * 64 + (((kk * 4 + quad) ^ (lr & 7)) << 3));
        }
}

__device__ __forceinline__ void load_b(FragB& fb, const ushort* Bb, int base,
                                       int lr, int quad)
{
    #pragma unroll
    for (int ni2 = 0; ni2 < 2; ni2++)
        #pragma unroll
        for (int kk = 0; kk < 2; kk++) {
            const int row = base + ni2 * 16 + lr;
            fb.f[ni2][kk] = *(const bf16x8*)(
                Bb + row * 64 + (((kk * 4 + quad) ^ (lr & 7)) << 3));
        }
}

__device__ __forceinline__ void mfma_quad(floatx4 (&acc)[8][4], const FragA& fa,
                                          const FragB& fb, int mh, int nh)
{
    #pragma unroll
    for (int mi2 = 0; mi2 < 4; mi2++)
        #pragma unroll
        for (int ni2 = 0; ni2 < 2; ni2++)
            #pragma unroll
            for (int kk = 0; kk < 2; kk++)
                acc[mh*4 + mi2][nh*2 + ni2] =
                    mfma_bf16(fa.f[mi2][kk], fb.f[ni2][kk],
                              acc[mh*4 + mi2][nh*2 + ni2]);
}

// stage one 64-row x 64-col block (blk in 0..3) of a [256][2048] bf16 panel
// into LDS (linear dest, inverse-swizzled global source: unit ^= row&7)
__device__ __forceinline__ void stage64(const ushort* __restrict__ gsrc,
                                        ushort* ldst, int blk, int k0, int tid)
{
    const int lane = tid & 63;
    const int w8   = tid >> 6;            // wave id, uniform
    const int rl   = lane >> 3;           // 0..7 (== row&7)
    const int u    = lane & 7;
    const int row  = (blk << 6) + (w8 << 3) + rl;
    const ushort* g = gsrc + (size_t)row * C_ + k0 + ((u ^ rl) << 3);
    async16(g, ldst + (blk << 12) + (w8 << 9));   // wave-uniform LDS base
}

__device__ __forceinline__ void kloop_8ph(
    const ushort* __restrict__ Ablk, const ushort* __restrict__ Bblk,
    ushort* lds, floatx4 (&acc)[8][4], int tid)
{
    const int lane = tid & 63;
    const int w    = tid >> 6;
    const int wr   = w >> 2;               // 0..1
    const int wc   = w & 3;                // 0..3
    const int lr   = lane & 15;
    const int quad = lane >> 4;

    // ---- prologue: stage K-tiles 0 (buf0) and 1 (buf1) ----
    #pragma unroll
    for (int blk = 0; blk < 4; blk++) {
        stage64(Ablk, lds,         blk, 0, tid);
        stage64(Bblk, lds + 32768, blk, 0, tid);
    }
    #pragma unroll
    for (int blk = 0; blk < 4; blk++) {
        stage64(Ablk, lds + 16384, blk, 64, tid);
        stage64(Bblk, lds + 49152, blk, 64, tid);
    }
    asm volatile("s_waitcnt vmcnt(8)" ::: "memory");   // tile 0 resident
    __builtin_amdgcn_sched_barrier(0);
    __builtin_amdgcn_s_barrier();

    FragA fa0, fa1;
    FragB fb0, fb1;

    #pragma unroll 2
    for (int t = 0; t < 32; ++t) {
        const int p = t & 1;
        ushort* Ab = lds + (p << 14);
        ushort* Bb = lds + 32768 + (p << 14);
        const int k2 = (t + 2) << 6;
        const bool st = (t < 30);

        // -------- phase 1: quadrant (m0, n0) --------
        load_a(fa0, Ab, wr * 128, lr, quad);
        load_b(fb0, Bb, wc * 64, lr, quad);
        __builtin_amdgcn_s_barrier();
        asm volatile("s_waitcnt lgkmcnt(0)" ::: "memory");
        __builtin_amdgcn_sched_barrier(0);
        __builtin_amdgcn_s_setprio(1);
        mfma_quad(acc, fa0, fb0, 0, 0);
        __builtin_amdgcn_s_setprio(0);
        __builtin_amdgcn_s_barrier();

        // -------- phase 2: quadrant (m0, n1) --------
        load_b(fb1, Bb, wc * 64 + 32, lr, quad);
        if (st) { stage64(Ablk, Ab, 0, k2, tid);
                  stage64(Ablk, Ab, 2, k2, tid); }
        __builtin_amdgcn_s_barrier();
        asm volatile("s_waitcnt lgkmcnt(0)" ::: "memory");
        __builtin_amdgcn_sched_barrier(0);
        __builtin_amdgcn_s_setprio(1);
        mfma_quad(acc, fa0, fb1, 0, 1);
        __builtin_amdgcn_s_setprio(0);
        __builtin_amdgcn_s_barrier();

        // -------- phase 3: quadrant (m1, n0) --------
        load_a(fa1, Ab, wr * 128 + 64, lr, quad);
        if (st) { stage64(Bblk, Bb, 0, k2, tid);
                  stage64(Bblk, Bb, 1, k2, tid);
                  stage64(Bblk, Bb, 2, k2, tid); }
        __builtin_amdgcn_s_barrier();
        asm volatile("s_waitcnt lgkmcnt(0)" ::: "memory");
        __builtin_amdgcn_sched_barrier(0);
        __builtin_amdgcn_s_setprio(1);
        mfma_quad(acc, fa1, fb0, 1, 0);
        __builtin_amdgcn_s_setprio(0);
        __builtin_amdgcn_s_barrier();

        // -------- phase 4: quadrant (m1, n1) --------
        if (st) { stage64(Bblk, Bb, 3, k2, tid);
                  stage64(Ablk, Ab, 1, k2, tid);
                  stage64(Ablk, Ab, 3, k2, tid); }
        if (st) asm volatile("s_waitcnt vmcnt(8)" ::: "memory");
        else    asm volatile("s_waitcnt vmcnt(0)" ::: "memory");
        __builtin_amdgcn_sched_barrier(0);
        __builtin_amdgcn_s_barrier();
        __builtin_amdgcn_s_setprio(1);
        mfma_quad(acc, fa1, fb1, 1, 1);
        __builtin_amdgcn_s_setprio(0);
        __builtin_amdgcn_s_barrier();
    }
}

// ---------------------------------------------------------------------------
// 8-phase proj GEMM: out[M][N] f32 = A_bf16 @ Bt_bf16^T. Grid 128 (8Nx16M).
// ---------------------------------------------------------------------------
__global__ __launch_bounds__(512, 2) void gemm_bt_8ph(
    const ushort* __restrict__ A, const ushort* __restrict__ Bt,
    float* __restrict__ Co)
{
    __shared__ __align__(16) ushort lds[65536];    // 128 KiB

    const int tid  = threadIdx.x;
    const int lane = tid & 63;
    const int w    = tid >> 6;
    const int wr   = w >> 2;
    const int wc   = w & 3;
    const int lr   = lane & 15;
    const int quad = lane >> 4;

    // bijective XCD swizzle (nwg=128, 128%8==0)
    int bid = (int)blockIdx.x;
    bid = (bid & 7) * 16 + (bid >> 3);
    const int bx = bid & 7;                // N-tile (8)
    const int by = bid >> 3;               // M-tile (16)

    const ushort* Ablk = A  + (size_t)(by * 256) * C_;
    const ushort* Bblk = Bt + (size_t)(bx * 256) * C_;

    floatx4 acc[8][4];
    #pragma unroll
    for (int i = 0; i < 8; i++)
        #pragma unroll
        for (int j = 0; j < 4; j++)
            acc[i][j] = (floatx4){0.f, 0.f, 0.f, 0.f};

    kloop_8ph(Ablk, Bblk, lds, acc, tid);

    const size_t row0 = (size_t)by * 256 + wr * 128;
    const size_t col0 = (size_t)bx * 256 + wc * 64;
    #pragma unroll
    for (int mi = 0; mi < 8; mi++)
        #pragma unroll
        for (int ni = 0; ni < 4; ni++)
            #pragma unroll
            for (int r = 0; r < 4; r++)
                Co[(row0 + mi*16 + quad*4 + r) * (size_t)C_ + col0 + ni*16 + lr]
                    = acc[mi][ni][r];
}

// ---------------------------------------------------------------------------
// 8-phase fused QKV GEMM. Grid 384 = 24 N-tiles x 16 M-tiles.
//   Per 256-col tile = 2 heads of one of q/k/v.
//   Epilogue (reuses the 128 KiB LDS):
//     q/k: acc -> LDS [t][256] (16B units ^ t&31) -> RoPE -> qb/kb [BH][T][D]
//     v:   acc -> LDS [c][256] transposed (units ^ c&31) -> vt [BH][D][T]
// ---------------------------------------------------------------------------
__global__ __launch_bounds__(512, 2) void gemm_qkv_8ph(
    const ushort* __restrict__ A, const ushort* __restrict__ Bt,
    const float* __restrict__ cosb, const float* __restrict__ sinb,
    ushort* __restrict__ qb, ushort* __restrict__ kbf, ushort* __restrict__ vt)
{
    __shared__ __align__(16) ushort lds[65536];    // 128 KiB

    const int tid  = threadIdx.x;
    const int lane = tid & 63;
    const int w    = tid >> 6;
    const int wr   = w >> 2;
    const int wc   = w & 3;
    const int lr   = lane & 15;
    const int quad = lane >> 4;

    // bijective XCD swizzle (nwg=384, 384%8==0)
    int bid = (int)blockIdx.x;
    bid = (bid & 7) * 48 + (bid >> 3);
    const int bx = bid % 24;               // N-tile
    const int by = bid / 24;               // M-tile

    const ushort* Ablk = A  + (size_t)(by * 256) * C_;
    const ushort* Bblk = Bt + (size_t)(bx * 256) * C_;

    floatx4 acc[8][4];
    #pragma unroll
    for (int i = 0; i < 8; i++)
        #pragma unroll
        for (int j = 0; j < 4; j++)
            acc[i][j] = (floatx4){0.f, 0.f, 0.f, 0.f};

    kloop_8ph(Ablk, Bblk, lds, acc, tid);

    // ---- epilogue ----
    const int qt  = bx >> 3;               // 0=q, 1=k, 2=v
    const int h0  = (bx & 7) << 1;         // first of 2 heads in this tile
    const int b   = by >> 3;
    const int t0g = (by & 7) << 8;

    __syncthreads();     // all DMA drained by t=30/31 vmcnt(0); reuse LDS

    if (qt < 2) {
        // acc -> LDS [t][256], 16B units XOR-swizzled by (t&31)
        #pragma unroll
        for (int mi = 0; mi < 8; mi++)
            #pragma unroll
            for (int ni = 0; ni < 4; ni++)
                #pragma unroll
                for (int r = 0; r < 4; r++) {
                    const int tt = wr * 128 + mi * 16 + quad * 4 + r;
                    const int cc = wc * 64 + ni * 16 + lr;
                    lds[tt * 256 + ((((cc >> 3) ^ (tt & 31)) << 3) | (cc & 7))]
                        = f2bf(acc[mi][ni][r]);
                }
        __syncthreads();

        // thread -> row t = tid>>1, head-half hsel = tid&1
        const int trow = tid >> 1;
        const int hsel = tid & 1;
        const int tg   = t0g + trow;
        const int bh   = b * 16 + h0 + hsel;
        ushort* outp = (qt == 0 ? qb : kbf) + ((size_t)bh * T_ + tg) * D_;
        const float4* cp4 = (const float4*)(cosb + (size_t)tg * 64);
        const float4* sp4 = (const float4*)(sinb + (size_t)tg * 64);
        const ushort* rowp = lds + trow * 256;
        const int tw = trow & 31;
        #pragma unroll
        for (int u = 0; u < 8; u++) {
            bf16x8 x1 = *(const bf16x8*)(rowp + (((hsel * 16 + u)     ^ tw) << 3));
            bf16x8 x2 = *(const bf16x8*)(rowp + (((hsel * 16 + 8 + u) ^ tw) << 3));
            float cc[8], ss[8];
            *(float4*)(cc)     = cp4[u * 2];
            *(float4*)(cc + 4) = cp4[u * 2 + 1];
            *(float4*)(ss)     = sp4[u * 2];
            *(float4*)(ss + 4) = sp4[u * 2 + 1];
            ushortx8 lo, hi;
            #pragma unroll
            for (int e = 0; e < 8; e++) {
                const float x1f = (float)x1[e];
                const float x2f = (float)x2[e];
                lo[e] = f2bf(x1f * cc[e] - x2f * ss[e]);
                hi[e] = f2bf(x1f * ss[e] + x2f * cc[e]);
            }
            *(ushortx8*)(outp + u * 8)      = lo;
            *(ushortx8*)(outp + 64 + u * 8) = hi;
        }
    } else {
        // v: acc -> LDS [c][256] (t-major within row), units swizzled by c&31
        #pragma unroll
        for (int mi = 0; mi < 8; mi++)
            #pragma unroll
            for (int ni = 0; ni < 4; ni++)
                #pragma unroll
                for (int r = 0; r < 4; r++) {
                    const int tt = wr * 128 + mi * 16 + quad * 4 + r;
                    const int cc = wc * 64 + ni * 16 + lr;
                    lds[cc * 256 + ((((tt >> 3) ^ (cc & 31)) << 3) | (tt & 7))]
                        = f2bf(acc[mi][ni][r]);
                }
        __syncthreads();

        const int c  = tid >> 1;           // local column 0..255
        const int hT = tid & 1;            // t-half (128 each)
        const int hh = c >> 7;             // head within tile
        const int d  = c & 127;
        const int bh = b * 16 + h0 + hh;
        const ushort* rowp = lds + c * 256;
        const int cw = c & 31;
        ushort* outp = vt + ((size_t)bh * D_ + d) * T_ + t0g + hT * 128;
        #pragma unroll
        for (int u = 0; u < 16; u++) {
            bf16x8 vv = *(const bf16x8*)(rowp + (((hT * 16 + u) ^ cw) << 3));
            *(bf16x8*)(outp + u * 8) = vv;
        }
    }
}

// ---------------------------------------------------------------------------
// Cooperative causal flash attention, static-shift softmax.
// Output bf16 [M][C] so the proj GEMM consumes it directly.
// ---------------------------------------------------------------------------
__global__ __launch_bounds__(256, 4) void flash_attn(
    const ushort* __restrict__ qb, const ushort* __restrict__ kb,
    const ushort* __restrict__ vt, ushort* __restrict__ attnoutb)
{
    __shared__ __align__(16) ushort kt_s[64 * 128];      // [key][d], units ^key
    __shared__ __align__(16) ushort vt_s[128 * 64];      // [d][key], units ^d
    __shared__ __align__(16) ushort pl_s[4][16 * 40];    // per-wave P tile

    const int w    = threadIdx.x >> 6;
    const int lane = threadIdx.x & 63;
    const int lr   = lane & 15;
    const int quad = lane >> 4;

    const int bh = blockIdx.x & 31;
    const int m  = 31 - (blockIdx.x >> 5);    // longest key-ranges first
    const int qt = 4 * m + w;
    const int qbase = qt * 16;
    const int nk = m + 1;
    const int bb = bh >> 4, hh = bh & 15;

    const ushort* kbp = kb + (size_t)bh * T_ * D_;
    const ushort* vbp = vt + (size_t)bh * D_ * T_;
    ushort* pl = pl_s[w];

    bf16x8 qf[4];
    const ushort* qrow = qb + ((size_t)bh * T_ + qbase + lr) * D_ + quad * 8;
    #pragma unroll
    for (int kc = 0; kc < 4; kc++)
        qf[kc] = *(const bf16x8*)(qrow + kc * 32);

    floatx4 o[8];
    #pragma unroll
    for (int dc = 0; dc < 8; dc++) o[dc] = (floatx4){0.f, 0.f, 0.f, 0.f};
    floatx4 lac = (floatx4){0.f, 0.f, 0.f, 0.f};

    const __bf16 one = (__bf16)1.0f;
    const bf16x8 ones = {one, one, one, one, one, one, one, one};
    const float SCL  = 0.08838834764831845f * 1.4426950408889634f;
    const float BIAS = 23.083120654223414f;

    const int krow4 = lane >> 4;
    const int kunit = lane & 15;
    const int vrow8 = lane >> 3;
    const int vunit = lane & 7;

    for (int kt = 0; kt < nk; ++kt) {
        const int kb0 = kt * 64;
        __syncthreads();
        #pragma unroll
        for (int j = 0; j < 4; j++) {
            const int row = w * 16 + j * 4 + krow4;
            const ushort* gp = kbp + (size_t)(kb0 + row) * D_
                                   + ((kunit ^ (row & 15)) << 3);
            async16(gp, kt_s + (w * 16 + j * 4) * 128);
        }
        #pragma unroll
        for (int j = 0; j < 4; j++) {
            const int row = w * 32 + j * 8 + vrow8;
            const ushort* gp = vbp + (size_t)row * T_ + kb0
                                   + ((vunit ^ (row & 7)) << 3);
            async16(gp, vt_s + (w * 32 + j * 8) * 64);
        }
        __syncthreads();

        #pragma unroll
        for (int half = 0; half < 2; ++half) {
            floatx4 st[2];
            #pragma unroll
            for (int jj = 0; jj < 2; ++jj) {
                const int j = half * 2 + jj;
                floatx4 s = (floatx4){0.f, 0.f, 0.f, 0.f};
                const int kl = j * 16 + lr;
                #pragma unroll
                for (int kc = 0; kc < 4; kc++) {
                    bf16x8 af = *(const bf16x8*)(
                        kt_s + kl * 128 + ((((kc << 2) | quad) ^ lr) << 3));
                    s = mfma_bf16(af, qf[kc], s);
                }
                st[jj] = s;
            }
            #pragma unroll
            for (int jj = 0; jj < 2; ++jj) {
                const int j = half * 2 + jj;
                const int kg0 = kb0 + j * 16 + quad * 4;
                float p[4];
                #pragma unroll
                for (int r = 0; r < 4; r++) {
                    float e = __builtin_amdgcn_exp2f(fmaf(st[jj][r], SCL, -BIAS));
                    p[r] = (kg0 + r > qbase + lr) ? 0.f : e;
                }
                uint2 pk;
                pk.x = (uint32_t)f2bf(p[0]) | ((uint32_t)f2bf(p[1]) << 16);
                pk.y = (uint32_t)f2bf(p[2]) | ((uint32_t)f2bf(p[3]) << 16);
                *(uint2*)(pl + lr * 40 + jj * 16 + quad * 4) = pk;
            }
            bf16x8 pf = *(const bf16x8*)(pl + lr * 40 + quad * 8);
            lac = mfma_bf16(pf, ones, lac);
            #pragma unroll
            for (int dc = 0; dc < 8; dc++) {
                const int d = dc * 16 + lr;
                bf16x8 vf = *(const bf16x8*)(
                    vt_s + d * 64 + ((((half << 2) | quad) ^ (lr & 7)) << 3));
                o[dc] = mfma_bf16(pf, vf, o[dc]);
            }
        }
    }

    #pragma unroll
    for (int dc = 0; dc < 8; dc++)
        #pragma unroll
        for (int r = 0; r < 4; r++) {
            const int trow = qbase + quad * 4 + r;
            attnoutb[((size_t)(bb * T_ + trow)) * C_ + hh * D_ + dc * 16 + lr]
                = f2bf(o[dc][r] / lac[r]);
        }
}

// ---------------------------------------------------------------------------
extern "C" void kernel_launch(void* const* d_in, const int* in_sizes, int n_in,
                              void* d_out, int out_size, void* d_ws, size_t ws_size,
                              hipStream_t stream)
{
    (void)in_sizes; (void)n_in; (void)out_size; (void)ws_size;
    const float* x     = (const float*)d_in[0];
    const float* cosb  = (const float*)d_in[1];
    const float* sinb  = (const float*)d_in[2];
    const float* Wqkv  = (const float*)d_in[3];
    const float* Wproj = (const float*)d_in[4];
    float* out = (float*)d_out;

    // Workspace (117,440,512 B used):
    //  xb   [M][C] bf16        @ 0          (16,777,216)
    //  Wtq  [3C][C] bf16       @ 16777216   (25,165,824)
    //  Wtp  [C][C] bf16        @ 41943040   ( 8,388,608)
    //  qb   [BH][T][D] bf16    @ 50331648   (16,777,216)
    //  kb   [BH][T][D] bf16    @ 67108864   (16,777,216)
    //  vt   [BH][D][T] bf16    @ 83886080   (16,777,216)
    //  attn [M][C] bf16        @ 100663296  (16,777,216)
    char* ws = (char*)d_ws;
    ushort* xb       = (ushort*)(ws);
    ushort* Wtq      = (ushort*)(ws + 16777216);
    ushort* Wtp      = (ushort*)(ws + 41943040);
    ushort* qb       = (ushort*)(ws + 50331648);
    ushort* kbf      = (ushort*)(ws + 67108864);
    ushort* vt       = (ushort*)(ws + 83886080);
    ushort* attnoutb = (ushort*)(ws + 100663296);

    dim3 tb32(32, 8);
    transpose_w<<<dim3(3 * C_ / 32, C_ / 32), tb32, 0, stream>>>(Wqkv, Wtq, C_, 3 * C_);
    transpose_w<<<dim3(C_ / 32, C_ / 32),     tb32, 0, stream>>>(Wproj, Wtp, C_, C_);
    convert_bf16<<<(M_ * C_ / 4) / 256, 256, 0, stream>>>(x, xb);

    gemm_qkv_8ph<<<384, 512, 0, stream>>>(xb, Wtq, cosb, sinb, qb, kbf, vt);

    flash_attn<<<BH_ * 32, 256, 0, stream>>>(qb, kbf, vt, attnoutb);

    gemm_bt_8ph<<<128, 512, 0, stream>>>(attnoutb, Wtp, out);
}